// Round 9
// baseline (109.037 us; speedup 1.0000x reference)
//
#include <hip/hip_runtime.h>
#include <hip/hip_fp16.h>
#include <math.h>

// ---------------------------------------------------------------------------
// 2-layer GCN on MI355X. N=50000 (<2^16), E=800000, C: 64 -> 64 -> 40.
// hs16[i] = (x@W1)[i] (fp16, unscaled);
// hs8[i]  = fp8_e4m3(hs16[i] * dinv[i])   (pre-scaled in k_build: gather1
//           does PURE row sums -- no per-edge dinv probes);
// h1b[d] = relu((hs8[d] + sum_e hs8[src]) * dinv[d] + b1);
// hs2[i] = (h1b@W2)[i]*dinv[i] (fp16);
// out[d] = log_softmax((hs2[d] + sum_e hs2[src]) * dinv[d] + b2).
//
// 5 dispatches + 1 H2D memcpy node:
//   memcpyAsync: bcur[b] = b*SLACK.
//   k_part_gemm: blocks [0,npart) partition edges into slack dst-buckets
//                (single-pass: 8KB LDS stash + histogram; low-dword int64
//                reads). Blocks [npart,..) run LDS-tiled x@W1, fp16 out.
//   k_build:     one wg per 256-row bucket: degree -> scan -> row_beg/
//                row_end/dinv -> bucket-local ushort CSR -> NEW: convert
//                this bucket's hs16 rows to dinv-prescaled fp8 (32KB read +
//                16KB write per block -- cheap at 196-block parallelism,
//                unlike r3's 512KB fp16 buckets).
//   k_gather_relu64: wave/dst-row (1 row/wave, 50000 waves); 8 edges x
//                8 lanes x uint2 (8 fp8 ch); packed cvt; PLAIN ADDS (no
//                dinv fmaf); 3 shfl_xor butterflies; bias+relu -> fp16.
//   k_gemm<40>:  LDS-tiled h1b@W2, dinv-scaled fp16 out.
//   k_gather_lsm40: wave/dst-row; 4 edges x 16 lanes x 8B; fused bias +
//                log_softmax -> fp32.
// Lessons: random small global stores amplify unless bucket-local (r3-5);
// gather fusion variants lose ~10us (r10/r11); bulk RMW in low-parallelism
// kernel loses (r12); fixed-cost cuts won 7.2us (r13); chain-halving null
// (r14); fp8 byte-halving only -1us (r17) -> gathers are TA PROBE-bound
// (cost per distinct cache line, not per byte): cut probes, not bytes.
// ---------------------------------------------------------------------------

#define SHIFT   8
#define RPB     256
#define NBMAX   256
#define SLACK   8192
#define CHUNK_P 2048

typedef float v2f __attribute__((ext_vector_type(2)));

// --- fused: edge partition (blocks < npart) || x@W1 GEMM (rest) -------------
__global__ void k_part_gemm(const int* __restrict__ ei32,
                            int* __restrict__ bcur,
                            unsigned int* __restrict__ ebkt, int E, int nb,
                            int npart,
                            const float* __restrict__ x,
                            const float* __restrict__ W1,
                            __half* __restrict__ hs16, int n) {
    __shared__ __align__(16) float smem[2 * 64 * 68];
    if ((int)blockIdx.x < npart) {
        // ---------------- partition branch (single-pass, LDS stash) --------
        int* cnt   = (int*)smem;          // [256]
        int* rbase = cnt + 256;           // [256]
        int* is64p = rbase + 256;         // [1]
        int* stash = is64p + 1;           // [2048] packed (dst16|src16)
        int t = threadIdx.x;
        cnt[t] = 0;
        if (t == 0) {
            int is64 = 1;
            for (int i = 0; i < 64; ++i)
                if (ei32[2 * i + 1] != 0) { is64 = 0; break; }
            *is64p = is64;
        }
        __syncthreads();
        int is64 = *is64p;
        int lo = blockIdx.x * CHUNK_P;
        int hi = lo + CHUNK_P; if (hi > E) hi = E;
        for (int e = lo + t; e < hi; e += 256) {
            int s, d;
            if (is64) { s = ei32[2 * e]; d = ei32[2 * (E + e)]; }  // low dwords
            else      { s = ei32[e];     d = ei32[E + e]; }
            stash[e - lo] = (int)(((unsigned int)d << 16) | (unsigned int)s);
            atomicAdd(&cnt[d >> SHIFT], 1);
        }
        __syncthreads();
        {
            int c = cnt[t];
            rbase[t] = c ? atomicAdd(&bcur[t], c) : 0;
            cnt[t] = 0;
        }
        __syncthreads();
        for (int e = lo + t; e < hi; e += 256) {
            unsigned int v = (unsigned int)stash[e - lo];
            int b = (int)(v >> 16) >> SHIFT;
            int pos = rbase[b] + atomicAdd(&cnt[b], 1);
            ebkt[pos] = (((v >> 16) & (RPB - 1)) << 16) | (v & 0xffffu);
        }
    } else {
        // ---------------- GEMM branch (x@W1, unscaled fp16 out) -------------
        float* Wl = smem;
        float* Xl = smem + 64 * 68;
        int t  = threadIdx.x;
        int tr = t >> 4, tc = t & 15;
        int base = (blockIdx.x - npart) * 64;

        for (int i = t; i < 64 * 17; i += 256) {
            int k = i / 17, c4 = (i % 17) * 4;
            float4 w = make_float4(0.f, 0.f, 0.f, 0.f);
            if (c4 < 64) w = *(const float4*)&W1[k * 64 + c4];
            *(float4*)&Wl[k * 68 + c4] = w;
        }
        for (int rr = tr; rr < 64; rr += 16) {
            int row = base + rr; if (row >= n) row = n - 1;
            float4 v = *(const float4*)&x[(size_t)row * 64 + tc * 4];
            Xl[(tc * 4 + 0) * 68 + rr] = v.x;
            Xl[(tc * 4 + 1) * 68 + rr] = v.y;
            Xl[(tc * 4 + 2) * 68 + rr] = v.z;
            Xl[(tc * 4 + 3) * 68 + rr] = v.w;
        }
        __syncthreads();

        float acc[4][4] = {{0.f}};
#pragma unroll 8
        for (int k = 0; k < 64; ++k) {
            float4 xv = *(const float4*)&Xl[k * 68 + tr * 4];
            float4 wv = *(const float4*)&Wl[k * 68 + tc * 4];
            acc[0][0] = fmaf(xv.x, wv.x, acc[0][0]);
            acc[0][1] = fmaf(xv.x, wv.y, acc[0][1]);
            acc[0][2] = fmaf(xv.x, wv.z, acc[0][2]);
            acc[0][3] = fmaf(xv.x, wv.w, acc[0][3]);
            acc[1][0] = fmaf(xv.y, wv.x, acc[1][0]);
            acc[1][1] = fmaf(xv.y, wv.y, acc[1][1]);
            acc[1][2] = fmaf(xv.y, wv.z, acc[1][2]);
            acc[1][3] = fmaf(xv.y, wv.w, acc[1][3]);
            acc[2][0] = fmaf(xv.z, wv.x, acc[2][0]);
            acc[2][1] = fmaf(xv.z, wv.y, acc[2][1]);
            acc[2][2] = fmaf(xv.z, wv.z, acc[2][2]);
            acc[2][3] = fmaf(xv.z, wv.w, acc[2][3]);
            acc[3][0] = fmaf(xv.w, wv.x, acc[3][0]);
            acc[3][1] = fmaf(xv.w, wv.y, acc[3][1]);
            acc[3][2] = fmaf(xv.w, wv.z, acc[3][2]);
            acc[3][3] = fmaf(xv.w, wv.w, acc[3][3]);
        }
#pragma unroll
        for (int i = 0; i < 4; ++i) {
            int r = base + tr * 4 + i;
            if (r >= n) break;
            __half2 p0 = __floats2half2_rn(acc[i][0], acc[i][1]);
            __half2 p1 = __floats2half2_rn(acc[i][2], acc[i][3]);
            *(__half2*)&hs16[(size_t)r * 64 + tc * 4]     = p0;
            *(__half2*)&hs16[(size_t)r * 64 + tc * 4 + 2] = p1;
        }
    }
}

// --- per-bucket (256 rows): degree, scan, row_beg/row_end/dinv, CSR fill, ---
// --- then hs8[row] = fp8(hs16[row] * dinv[row]) for this bucket's rows. -----
__global__ void k_build(const unsigned int* __restrict__ ebkt,
                        const int* __restrict__ bcur,
                        int* __restrict__ row_beg, int* __restrict__ row_end,
                        float* __restrict__ dinv,
                        unsigned short* __restrict__ csr_src,
                        const __half* __restrict__ hs16,
                        unsigned char* __restrict__ hs8, int N) {
    __shared__ int cnt[RPB];
    __shared__ int ssum[RPB];
    __shared__ float dinv_l[RPB];
    int t = threadIdx.x, b = blockIdx.x;
    int rows0 = b << SHIFT;
    int nrows = N - rows0; if (nrows > RPB) nrows = RPB;
    cnt[t] = 0;
    __syncthreads();
    int lo = b * SLACK, hi = bcur[b];
    for (int e = lo + t; e < hi; e += 256)
        atomicAdd(&cnt[ebkt[e] >> 16], 1);
    __syncthreads();
    int c = cnt[t];
    ssum[t] = c;
    __syncthreads();
    for (int off = 1; off < 256; off <<= 1) {
        int u = (t >= off) ? ssum[t - off] : 0;
        __syncthreads();
        ssum[t] += u;
        __syncthreads();
    }
    int beg = lo + ssum[t] - c;          // exclusive prefix
    float dvt = rsqrtf((float)c + 1.0f);
    dinv_l[t] = dvt;
    int row = rows0 + t;
    if (row < N) {
        row_beg[row] = beg; row_end[row] = beg + c;
        dinv[row] = dvt;
    }
    cnt[t] = beg;
    __syncthreads();                      // makes dinv_l + cnt visible
    for (int e = lo + t; e < hi; e += 256) {
        unsigned int v = ebkt[e];
        int pos = atomicAdd(&cnt[v >> 16], 1);
        csr_src[pos] = (unsigned short)(v & 0xffffu);
    }
    // ---- dinv-prescaled fp8 conversion of this bucket's rows ---------------
    // piece = 8 channels: uint4 fp16 in -> uint2 fp8 out; coalesced.
    for (int i = t; i < nrows * 8; i += 256) {
        int r = i >> 3, piece = i & 7;
        float dv = dinv_l[r];
        uint4 u = ((const uint4*)(hs16 + ((size_t)(rows0 + r) << 6)))[piece];
        float2 f0 = __half22float2(*(__half2*)&u.x);
        float2 f1 = __half22float2(*(__half2*)&u.y);
        float2 f2 = __half22float2(*(__half2*)&u.z);
        float2 f3 = __half22float2(*(__half2*)&u.w);
        unsigned int w0, w1;
        w0 = (unsigned int)__builtin_amdgcn_cvt_pk_fp8_f32(
                f0.x * dv, f0.y * dv, 0, false);
        w0 = (unsigned int)__builtin_amdgcn_cvt_pk_fp8_f32(
                f1.x * dv, f1.y * dv, (int)w0, true);
        w1 = (unsigned int)__builtin_amdgcn_cvt_pk_fp8_f32(
                f2.x * dv, f2.y * dv, 0, false);
        w1 = (unsigned int)__builtin_amdgcn_cvt_pk_fp8_f32(
                f3.x * dv, f3.y * dv, (int)w1, true);
        uint2 st; st.x = w0; st.y = w1;
        ((uint2*)(hs8 + ((size_t)(rows0 + r) << 6)))[piece] = st;
    }
}

// --- Gather C=64 fp8 (pre-scaled): 8 edges x 8 lanes x uint2; plain adds; ---
// --- fused bias + relu -> fp16 h1b. No per-edge dinv probes. ----------------
__global__ void k_gather_relu64(const unsigned char* __restrict__ hs8,
                                const int* __restrict__ rbg,
                                const int* __restrict__ ren,
                                const unsigned short* __restrict__ ci,
                                const float* __restrict__ dinv,
                                const float* __restrict__ bias,
                                __half* __restrict__ out, int n) {
    int row = blockIdx.x * 4 + (threadIdx.x >> 6);
    if (row >= n) return;
    int lane = threadIdx.x & 63;
    int g = lane >> 3, q = lane & 7;     // edge slot 0..7, 8B chunk 0..7
    int beg = rbg[row], end = ren[row];

    // hoisted epilogue loads (issue under the gather loop)
    float dv = dinv[row];
    uint2 su = ((const uint2*)(hs8 + ((size_t)row << 6)))[q];

    float4 aa = make_float4(0.f, 0.f, 0.f, 0.f);
    float4 ab = make_float4(0.f, 0.f, 0.f, 0.f);
    for (int base = beg; base < end; base += 64) {
        int mm = end - base; if (mm > 64) mm = 64;
        int idx = (lane < mm) ? (int)ci[base + lane] : 0;
        for (int j = 0; 8 * j < mm; ++j) {
            int e = 8 * j + g;
            int s = __shfl(idx, e, 64);
            if (base + e < end) {
                uint2 u = ((const uint2*)(hs8 + ((size_t)s << 6)))[q];
                v2f f0 = __builtin_amdgcn_cvt_pk_f32_fp8((int)u.x, false);
                v2f f1 = __builtin_amdgcn_cvt_pk_f32_fp8((int)u.x, true);
                v2f f2 = __builtin_amdgcn_cvt_pk_f32_fp8((int)u.y, false);
                v2f f3 = __builtin_amdgcn_cvt_pk_f32_fp8((int)u.y, true);
                aa.x += f0.x; aa.y += f0.y;
                aa.z += f1.x; aa.w += f1.y;
                ab.x += f2.x; ab.y += f2.y;
                ab.z += f3.x; ab.w += f3.y;
            }
        }
    }
#pragma unroll
    for (int o = 8; o < 64; o <<= 1) {
        aa.x += __shfl_xor(aa.x, o, 64); aa.y += __shfl_xor(aa.y, o, 64);
        aa.z += __shfl_xor(aa.z, o, 64); aa.w += __shfl_xor(aa.w, o, 64);
        ab.x += __shfl_xor(ab.x, o, 64); ab.y += __shfl_xor(ab.y, o, 64);
        ab.z += __shfl_xor(ab.z, o, 64); ab.w += __shfl_xor(ab.w, o, 64);
    }
    // epilogue on all lanes (values identical within each q); lanes<8 store
    v2f s0 = __builtin_amdgcn_cvt_pk_f32_fp8((int)su.x, false);
    v2f s1 = __builtin_amdgcn_cvt_pk_f32_fp8((int)su.x, true);
    v2f s2 = __builtin_amdgcn_cvt_pk_f32_fp8((int)su.y, false);
    v2f s3 = __builtin_amdgcn_cvt_pk_f32_fp8((int)su.y, true);
    float4 bv0 = *(const float4*)&bias[q * 8];
    float4 bv1 = *(const float4*)&bias[q * 8 + 4];
    float v0 = fmaxf((aa.x + s0.x) * dv + bv0.x, 0.f);
    float v1 = fmaxf((aa.y + s0.y) * dv + bv0.y, 0.f);
    float v2 = fmaxf((aa.z + s1.x) * dv + bv0.z, 0.f);
    float v3 = fmaxf((aa.w + s1.y) * dv + bv0.w, 0.f);
    float v4 = fmaxf((ab.x + s2.x) * dv + bv1.x, 0.f);
    float v5 = fmaxf((ab.y + s2.y) * dv + bv1.y, 0.f);
    float v6 = fmaxf((ab.z + s3.x) * dv + bv1.z, 0.f);
    float v7 = fmaxf((ab.w + s3.y) * dv + bv1.w, 0.f);
    if (lane < 8) {
        uint4 st;
        ((__half2*)&st)[0] = __floats2half2_rn(v0, v1);
        ((__half2*)&st)[1] = __floats2half2_rn(v2, v3);
        ((__half2*)&st)[2] = __floats2half2_rn(v4, v5);
        ((__half2*)&st)[3] = __floats2half2_rn(v6, v7);
        ((uint4*)(out + ((size_t)row << 6)))[q] = st;
    }
}

// --- LDS-tiled GEMM (layer 2): hs = (h1b@W2)*dinv, fp16 in/out, COUT=40. ----
template<int COUT>
__global__ void k_gemm(const __half* __restrict__ xin,
                       const float* __restrict__ W,
                       const float* __restrict__ dinv,
                       __half* __restrict__ hs, int n) {
    __shared__ float Wl[64 * 68];
    __shared__ float Xl[64 * 68];
    int t  = threadIdx.x;
    int tr = t >> 4, tc = t & 15;
    int base = blockIdx.x * 64;

    for (int i = t; i < 64 * 17; i += 256) {
        int k = i / 17, c4 = (i % 17) * 4;
        float4 w = make_float4(0.f, 0.f, 0.f, 0.f);
        if (c4 < COUT) w = *(const float4*)&W[k * COUT + c4];
        *(float4*)&Wl[k * 68 + c4] = w;
    }
    for (int rr = tr; rr < 64; rr += 16) {
        int row = base + rr; if (row >= n) row = n - 1;
        uint2 u = *(const uint2*)&xin[(size_t)row * 64 + tc * 4];
        float2 a = __half22float2(*(__half2*)&u.x);
        float2 c = __half22float2(*(__half2*)&u.y);
        Xl[(tc * 4 + 0) * 68 + rr] = a.x;
        Xl[(tc * 4 + 1) * 68 + rr] = a.y;
        Xl[(tc * 4 + 2) * 68 + rr] = c.x;
        Xl[(tc * 4 + 3) * 68 + rr] = c.y;
    }
    __syncthreads();

    float acc[4][4] = {{0.f}};
#pragma unroll 8
    for (int k = 0; k < 64; ++k) {
        float4 xv = *(const float4*)&Xl[k * 68 + tr * 4];
        float4 wv = *(const float4*)&Wl[k * 68 + tc * 4];
        acc[0][0] = fmaf(xv.x, wv.x, acc[0][0]);
        acc[0][1] = fmaf(xv.x, wv.y, acc[0][1]);
        acc[0][2] = fmaf(xv.x, wv.z, acc[0][2]);
        acc[0][3] = fmaf(xv.x, wv.w, acc[0][3]);
        acc[1][0] = fmaf(xv.y, wv.x, acc[1][0]);
        acc[1][1] = fmaf(xv.y, wv.y, acc[1][1]);
        acc[1][2] = fmaf(xv.y, wv.z, acc[1][2]);
        acc[1][3] = fmaf(xv.y, wv.w, acc[1][3]);
        acc[2][0] = fmaf(xv.z, wv.x, acc[2][0]);
        acc[2][1] = fmaf(xv.z, wv.y, acc[2][1]);
        acc[2][2] = fmaf(xv.z, wv.z, acc[2][2]);
        acc[2][3] = fmaf(xv.z, wv.w, acc[2][3]);
        acc[3][0] = fmaf(xv.w, wv.x, acc[3][0]);
        acc[3][1] = fmaf(xv.w, wv.y, acc[3][1]);
        acc[3][2] = fmaf(xv.w, wv.z, acc[3][2]);
        acc[3][3] = fmaf(xv.w, wv.w, acc[3][3]);
    }
#pragma unroll
    for (int i = 0; i < 4; ++i) {
        int r = base + tr * 4 + i;
        if (r >= n) break;
        float dv = dinv[r];
        __half2 p0 = __floats2half2_rn(acc[i][0] * dv, acc[i][1] * dv);
        __half2 p1 = __floats2half2_rn(acc[i][2] * dv, acc[i][3] * dv);
        if (tc * 4 + 3 < COUT) {
            *(__half2*)&hs[(size_t)r * COUT + tc * 4]     = p0;
            *(__half2*)&hs[(size_t)r * COUT + tc * 4 + 2] = p1;
        }
    }
}

// --- Gather C=40 + bias + log_softmax -> fp32. 4 edges x 16 lanes x 8B. -----
__global__ void k_gather_lsm40(const __half* __restrict__ hs,
                               const int* __restrict__ rbg,
                               const int* __restrict__ ren,
                               const unsigned short* __restrict__ ci,
                               const float* __restrict__ dinv,
                               const float* __restrict__ bias,
                               float* __restrict__ out, int n) {
    int row = blockIdx.x * 4 + (threadIdx.x >> 6);
    if (row >= n) return;
    int lane = threadIdx.x & 63;
    int g = lane >> 4, q = lane & 15;
    int beg = rbg[row], end = ren[row];

    // hoisted epilogue loads
    float dv = dinv[row];
    uint2 selfu = make_uint2(0u, 0u);
    if (q < 10)
        selfu = ((const uint2*)(hs + (size_t)row * 40))[q];

    float4 a = make_float4(0.f, 0.f, 0.f, 0.f);
    for (int base = beg; base < end; base += 64) {
        int mm = end - base; if (mm > 64) mm = 64;
        int idx = (lane < mm) ? (int)ci[base + lane] : 0;
        for (int j = 0; 4 * j < mm; ++j) {
            int s = __shfl(idx, 4 * j + g, 64);
            if (q < 10 && base + 4 * j + g < end) {
                uint2 u = ((const uint2*)(hs + (size_t)s * 40))[q];
                float2 f0 = __half22float2(*(__half2*)&u.x);
                float2 f1 = __half22float2(*(__half2*)&u.y);
                a.x += f0.x; a.y += f0.y; a.z += f1.x; a.w += f1.y;
            }
        }
    }
    a.x += __shfl_xor(a.x, 16, 64); a.y += __shfl_xor(a.y, 16, 64);
    a.z += __shfl_xor(a.z, 16, 64); a.w += __shfl_xor(a.w, 16, 64);
    a.x += __shfl_xor(a.x, 32, 64); a.y += __shfl_xor(a.y, 32, 64);
    a.z += __shfl_xor(a.z, 32, 64); a.w += __shfl_xor(a.w, 32, 64);

    float2 s0 = __half22float2(*(__half2*)&selfu.x);
    float2 s1 = __half22float2(*(__half2*)&selfu.y);
    float v0 = -INFINITY, v1 = -INFINITY, v2 = -INFINITY, v3 = -INFINITY;
    if (q < 10) {
        float4 bv = *(const float4*)&bias[q * 4];
        v0 = (a.x + s0.x) * dv + bv.x;
        v1 = (a.y + s0.y) * dv + bv.y;
        v2 = (a.z + s1.x) * dv + bv.z;
        v3 = (a.w + s1.y) * dv + bv.w;
    }
    float mx = fmaxf(fmaxf(v0, v1), fmaxf(v2, v3));
#pragma unroll
    for (int o = 1; o < 16; o <<= 1) mx = fmaxf(mx, __shfl_xor(mx, o, 64));
    float e0 = (q < 10) ? expf(v0 - mx) : 0.f;
    float e1 = (q < 10) ? expf(v1 - mx) : 0.f;
    float e2 = (q < 10) ? expf(v2 - mx) : 0.f;
    float e3 = (q < 10) ? expf(v3 - mx) : 0.f;
    float sm = (e0 + e1) + (e2 + e3);
#pragma unroll
    for (int o = 1; o < 16; o <<= 1) sm += __shfl_xor(sm, o, 64);
    if (lane < 16 && q < 10) {
        float ls = logf(sm);
        float4 r = make_float4(v0 - mx - ls, v1 - mx - ls,
                               v2 - mx - ls, v3 - mx - ls);
        *(float4*)&out[(size_t)row * 40 + q * 4] = r;
    }
}

extern "C" void kernel_launch(void* const* d_in, const int* in_sizes, int n_in,
                              void* d_out, int out_size, void* d_ws, size_t ws_size,
                              hipStream_t stream) {
    const float* x  = (const float*)d_in[0];
    const void*  ei = d_in[1];
    const float* W1 = (const float*)d_in[2];
    const float* b1 = (const float*)d_in[3];
    const float* W2 = (const float*)d_in[4];
    const float* b2 = (const float*)d_in[5];
    float* out = (float*)d_out;

    const int C_IN = 64;
    const int N = in_sizes[0] / C_IN;   // 50000
    const int E = in_sizes[1] / 2;      // 800000
    (void)n_in; (void)out_size; (void)ws_size;

    char* ws = (char*)d_ws;
    size_t off = 0;
    auto alloc = [&](size_t bytes) -> void* {
        void* p = ws + off;
        off += (bytes + 255) & ~(size_t)255;
        return p;
    };
    int*            bcur    = (int*)           alloc(NBMAX * 4);
    unsigned int*   ebkt    = (unsigned int*)  alloc((size_t)NBMAX * SLACK * 4);
    unsigned short* csr_src = (unsigned short*)alloc((size_t)NBMAX * SLACK * 2);
    int*            row_beg = (int*)           alloc((size_t)N * 4);
    int*            row_end = (int*)           alloc((size_t)N * 4);
    float*          dinv    = (float*)         alloc((size_t)N * 4);
    __half*         hs16    = (__half*)        alloc((size_t)N * 64 * 2);
    unsigned char*  hs8     = (unsigned char*) alloc((size_t)N * 64);
    __half*         h1b     = (__half*)        alloc((size_t)N * 64 * 2);
    __half*         hs2     = (__half*)        alloc((size_t)N * 40 * 2);

    const int nb    = (N + RPB - 1) >> SHIFT;         // 196
    const int ngrid = (N + 63) / 64;                  // 782
    const int npart = (E + CHUNK_P - 1) / CHUNK_P;    // 391

    // bcur init via H2D memcpy node (replaces the k_init dispatch)
    static int h_binit[NBMAX];
    for (int i = 0; i < NBMAX; ++i) h_binit[i] = i * SLACK;
    (void)hipMemcpyAsync(bcur, h_binit, NBMAX * sizeof(int),
                         hipMemcpyHostToDevice, stream);

    k_part_gemm<<<npart + ngrid, 256, 0, stream>>>(
        (const int*)ei, bcur, ebkt, E, nb, npart, x, W1, hs16, N);
    k_build<<<nb, 256, 0, stream>>>(ebkt, bcur, row_beg, row_end, dinv,
                                    csr_src, hs16, hs8, N);
    k_gather_relu64<<<(N + 3) / 4, 256, 0, stream>>>(
        hs8, row_beg, row_end, csr_src, dinv, b1, h1b, N);
    k_gemm<40><<<ngrid, 256, 0, stream>>>(h1b, W2, dinv, hs2, N);
    k_gather_lsm40<<<(N + 3) / 4, 256, 0, stream>>>(
        hs2, row_beg, row_end, csr_src, dinv, b2, out, N);
}

// Round 10
// 98.476 us; speedup vs baseline: 1.1072x; 1.1072x over previous
//
#include <hip/hip_runtime.h>
#include <hip/hip_fp16.h>
#include <math.h>

// ---------------------------------------------------------------------------
// 2-layer GCN on MI355X. N=50000 (<2^16), E=800000, C: 64 -> 64 -> 40.
// hs8[i] = fp8_e4m3((x@W1)[i])  (quantized in gemm1 epilogue; 3.2MB);
// h1b[d] = relu((hs8[d]*dinv[d] + sum_e hs8[src]*dinv[src]) * dinv[d] + b1);
// hs2[i] = (h1b@W2)[i]*dinv[i] (fp16);
// out[d] = log_softmax((hs2[d] + sum_e hs2[src]) * dinv[d] + b2).
//
// 5 dispatches + 1 H2D memcpy node (r8 structure = session best, + trims):
//   memcpyAsync: bcur[b] = b*SLACK.
//   k_part_gemm: blocks [0,npart) partition edges into slack dst-buckets.
//                CHUNK_P=4096 (was 2048): halves partition blocks -> halves
//                bcur atomic rounds; doubles per-bucket scatter run length
//                (16 consecutive ebkt entries = full 64B lines) cutting
//                random-store amplification. 16KB LDS stash. Blocks
//                [npart,..) run LDS-tiled x@W1, fp8 e4m3 out.
//   k_build:     one wg per 256-row bucket; WAVE-LEVEL shfl_up scan
//                (1 barrier, was 16) -> row_beg/row_end/dinv -> bucket-local
//                ushort CSR fill.
//   k_gather_relu64: wave/dst-row (1 row/wave, 50000 waves); 8 edges x
//                8 lanes x uint2 (8 fp8 ch); packed cvt_pk_f32_fp8;
//                dinv[src] fmaf (broadcast probe, measured ~free in r18);
//                3 shfl_xor butterflies; bias+relu -> fp16 h1b.
//   k_gemm<40>:  LDS-tiled h1b@W2, dinv-scaled fp16 out.
//   k_gather_lsm40: wave/dst-row; 4 edges x 16 lanes x 8B; fused bias +
//                log_softmax -> fp32.
// Lessons: random small global stores amplify unless bucket-local (r3-5);
// gather fusion loses ~10us (r10/r11); bulk RMW at low block-parallelism
// loses (r12); fixed-cost cuts won 7.2us (r13); gather chain-halving null
// (r14); fp8 byte-halving -1us (r17); dinv pre-scale pass lost 3.3us (r18:
// broadcast dinv probes were free) -> gathers are at their structural floor
// (scattered-vmem issue/miss-queue bound); only fixed costs remain.
// ---------------------------------------------------------------------------

#define SHIFT   8
#define RPB     256
#define NBMAX   256
#define SLACK   8192
#define CHUNK_P 4096

typedef float v2f __attribute__((ext_vector_type(2)));

// --- fused: edge partition (blocks < npart) || x@W1 GEMM (rest) -------------
__global__ void k_part_gemm(const int* __restrict__ ei32,
                            int* __restrict__ bcur,
                            unsigned int* __restrict__ ebkt, int E, int nb,
                            int npart,
                            const float* __restrict__ x,
                            const float* __restrict__ W1,
                            unsigned char* __restrict__ hs8, int n) {
    __shared__ __align__(16) float smem[2 * 64 * 68];
    if ((int)blockIdx.x < npart) {
        // ---------------- partition branch (single-pass, LDS stash) --------
        int* cnt   = (int*)smem;          // [256]
        int* rbase = cnt + 256;           // [256]
        int* is64p = rbase + 256;         // [1]
        int* stash = is64p + 1;           // [4096] packed (dst16|src16)
        int t = threadIdx.x;
        cnt[t] = 0;
        if (t == 0) {
            int is64 = 1;
            for (int i = 0; i < 64; ++i)
                if (ei32[2 * i + 1] != 0) { is64 = 0; break; }
            *is64p = is64;
        }
        __syncthreads();
        int is64 = *is64p;
        int lo = blockIdx.x * CHUNK_P;
        int hi = lo + CHUNK_P; if (hi > E) hi = E;
        for (int e = lo + t; e < hi; e += 256) {
            int s, d;
            if (is64) { s = ei32[2 * e]; d = ei32[2 * (E + e)]; }  // low dwords
            else      { s = ei32[e];     d = ei32[E + e]; }
            stash[e - lo] = (int)(((unsigned int)d << 16) | (unsigned int)s);
            atomicAdd(&cnt[d >> SHIFT], 1);
        }
        __syncthreads();
        {
            int c = cnt[t];
            rbase[t] = c ? atomicAdd(&bcur[t], c) : 0;
            cnt[t] = 0;
        }
        __syncthreads();
        for (int e = lo + t; e < hi; e += 256) {
            unsigned int v = (unsigned int)stash[e - lo];
            int b = (int)(v >> 16) >> SHIFT;
            int pos = rbase[b] + atomicAdd(&cnt[b], 1);
            ebkt[pos] = (((v >> 16) & (RPB - 1)) << 16) | (v & 0xffffu);
        }
    } else {
        // ---------------- GEMM branch (x@W1, fp8 e4m3 out) ------------------
        float* Wl = smem;
        float* Xl = smem + 64 * 68;
        int t  = threadIdx.x;
        int tr = t >> 4, tc = t & 15;
        int base = (blockIdx.x - npart) * 64;

        for (int i = t; i < 64 * 17; i += 256) {
            int k = i / 17, c4 = (i % 17) * 4;
            float4 w = make_float4(0.f, 0.f, 0.f, 0.f);
            if (c4 < 64) w = *(const float4*)&W1[k * 64 + c4];
            *(float4*)&Wl[k * 68 + c4] = w;
        }
        for (int rr = tr; rr < 64; rr += 16) {
            int row = base + rr; if (row >= n) row = n - 1;
            float4 v = *(const float4*)&x[(size_t)row * 64 + tc * 4];
            Xl[(tc * 4 + 0) * 68 + rr] = v.x;
            Xl[(tc * 4 + 1) * 68 + rr] = v.y;
            Xl[(tc * 4 + 2) * 68 + rr] = v.z;
            Xl[(tc * 4 + 3) * 68 + rr] = v.w;
        }
        __syncthreads();

        float acc[4][4] = {{0.f}};
#pragma unroll 8
        for (int k = 0; k < 64; ++k) {
            float4 xv = *(const float4*)&Xl[k * 68 + tr * 4];
            float4 wv = *(const float4*)&Wl[k * 68 + tc * 4];
            acc[0][0] = fmaf(xv.x, wv.x, acc[0][0]);
            acc[0][1] = fmaf(xv.x, wv.y, acc[0][1]);
            acc[0][2] = fmaf(xv.x, wv.z, acc[0][2]);
            acc[0][3] = fmaf(xv.x, wv.w, acc[0][3]);
            acc[1][0] = fmaf(xv.y, wv.x, acc[1][0]);
            acc[1][1] = fmaf(xv.y, wv.y, acc[1][1]);
            acc[1][2] = fmaf(xv.y, wv.z, acc[1][2]);
            acc[1][3] = fmaf(xv.y, wv.w, acc[1][3]);
            acc[2][0] = fmaf(xv.z, wv.x, acc[2][0]);
            acc[2][1] = fmaf(xv.z, wv.y, acc[2][1]);
            acc[2][2] = fmaf(xv.z, wv.z, acc[2][2]);
            acc[2][3] = fmaf(xv.z, wv.w, acc[2][3]);
            acc[3][0] = fmaf(xv.w, wv.x, acc[3][0]);
            acc[3][1] = fmaf(xv.w, wv.y, acc[3][1]);
            acc[3][2] = fmaf(xv.w, wv.z, acc[3][2]);
            acc[3][3] = fmaf(xv.w, wv.w, acc[3][3]);
        }
#pragma unroll
        for (int i = 0; i < 4; ++i) {
            int r = base + tr * 4 + i;
            if (r >= n) break;
            unsigned int w;
            w = (unsigned int)__builtin_amdgcn_cvt_pk_fp8_f32(
                    acc[i][0], acc[i][1], 0, false);
            w = (unsigned int)__builtin_amdgcn_cvt_pk_fp8_f32(
                    acc[i][2], acc[i][3], (int)w, true);
            ((unsigned int*)(hs8 + ((size_t)r << 6)))[tc] = w;
        }
    }
}

// --- per-bucket (256 rows): degree, wave-scan, row_beg/row_end/dinv, CSR ----
__global__ void k_build(const unsigned int* __restrict__ ebkt,
                        const int* __restrict__ bcur,
                        int* __restrict__ row_beg, int* __restrict__ row_end,
                        float* __restrict__ dinv,
                        unsigned short* __restrict__ csr_src, int N) {
    __shared__ int cnt[RPB];
    __shared__ int wtot[4];
    int t = threadIdx.x, b = blockIdx.x;
    int rows0 = b << SHIFT;
    cnt[t] = 0;
    __syncthreads();
    int lo = b * SLACK, hi = bcur[b];
    for (int e = lo + t; e < hi; e += 256)
        atomicAdd(&cnt[ebkt[e] >> 16], 1);
    __syncthreads();
    int c = cnt[t];
    // wave-level inclusive scan (64 lanes), then cross-wave fixup: 1 barrier.
    int lane = t & 63, w = t >> 6;
    int sc = c;
#pragma unroll
    for (int o = 1; o < 64; o <<= 1) {
        int u = __shfl_up(sc, o, 64);
        if (lane >= o) sc += u;
    }
    if (lane == 63) wtot[w] = sc;
    __syncthreads();
    int wbase = 0;
#pragma unroll
    for (int ww = 0; ww < 3; ++ww)
        if (ww < w) wbase += wtot[ww];
    int beg = lo + wbase + sc - c;       // exclusive prefix
    int row = rows0 + t;
    if (row < N) {
        row_beg[row] = beg; row_end[row] = beg + c;
        dinv[row] = rsqrtf((float)c + 1.0f);
    }
    cnt[t] = beg;
    __syncthreads();
    for (int e = lo + t; e < hi; e += 256) {
        unsigned int v = ebkt[e];
        int pos = atomicAdd(&cnt[v >> 16], 1);
        csr_src[pos] = (unsigned short)(v & 0xffffu);
    }
}

// --- Gather C=64 fp8: 8 edges x 8 lanes x uint2 (8 fp8 ch, packed cvt); -----
// --- fused dinv[src] scale + bias + relu -> fp16 h1b. -----------------------
__global__ void k_gather_relu64(const unsigned char* __restrict__ hs8,
                                const int* __restrict__ rbg,
                                const int* __restrict__ ren,
                                const unsigned short* __restrict__ ci,
                                const float* __restrict__ dinv,
                                const float* __restrict__ bias,
                                __half* __restrict__ out, int n) {
    int row = blockIdx.x * 4 + (threadIdx.x >> 6);
    if (row >= n) return;
    int lane = threadIdx.x & 63;
    int g = lane >> 3, q = lane & 7;     // edge slot 0..7, 8B chunk 0..7
    int beg = rbg[row], end = ren[row];

    // hoisted epilogue loads (issue under the gather loop)
    float dv = dinv[row];
    uint2 su = ((const uint2*)(hs8 + ((size_t)row << 6)))[q];

    float4 aa = make_float4(0.f, 0.f, 0.f, 0.f);
    float4 ab = make_float4(0.f, 0.f, 0.f, 0.f);
    for (int base = beg; base < end; base += 64) {
        int mm = end - base; if (mm > 64) mm = 64;
        int idx = (lane < mm) ? (int)ci[base + lane] : 0;
        for (int j = 0; 8 * j < mm; ++j) {
            int e = 8 * j + g;
            int s = __shfl(idx, e, 64);
            if (base + e < end) {
                float ds = dinv[s];
                uint2 u = ((const uint2*)(hs8 + ((size_t)s << 6)))[q];
                v2f f0 = __builtin_amdgcn_cvt_pk_f32_fp8((int)u.x, false);
                v2f f1 = __builtin_amdgcn_cvt_pk_f32_fp8((int)u.x, true);
                v2f f2 = __builtin_amdgcn_cvt_pk_f32_fp8((int)u.y, false);
                v2f f3 = __builtin_amdgcn_cvt_pk_f32_fp8((int)u.y, true);
                aa.x = fmaf(f0.x, ds, aa.x); aa.y = fmaf(f0.y, ds, aa.y);
                aa.z = fmaf(f1.x, ds, aa.z); aa.w = fmaf(f1.y, ds, aa.w);
                ab.x = fmaf(f2.x, ds, ab.x); ab.y = fmaf(f2.y, ds, ab.y);
                ab.z = fmaf(f3.x, ds, ab.z); ab.w = fmaf(f3.y, ds, ab.w);
            }
        }
    }
#pragma unroll
    for (int o = 8; o < 64; o <<= 1) {
        aa.x += __shfl_xor(aa.x, o, 64); aa.y += __shfl_xor(aa.y, o, 64);
        aa.z += __shfl_xor(aa.z, o, 64); aa.w += __shfl_xor(aa.w, o, 64);
        ab.x += __shfl_xor(ab.x, o, 64); ab.y += __shfl_xor(ab.y, o, 64);
        ab.z += __shfl_xor(ab.z, o, 64); ab.w += __shfl_xor(ab.w, o, 64);
    }
    // epilogue on all lanes (values identical within each q); lanes<8 store
    v2f s0 = __builtin_amdgcn_cvt_pk_f32_fp8((int)su.x, false);
    v2f s1 = __builtin_amdgcn_cvt_pk_f32_fp8((int)su.x, true);
    v2f s2 = __builtin_amdgcn_cvt_pk_f32_fp8((int)su.y, false);
    v2f s3 = __builtin_amdgcn_cvt_pk_f32_fp8((int)su.y, true);
    float4 bv0 = *(const float4*)&bias[q * 8];
    float4 bv1 = *(const float4*)&bias[q * 8 + 4];
    float v0 = fmaxf((aa.x + s0.x * dv) * dv + bv0.x, 0.f);
    float v1 = fmaxf((aa.y + s0.y * dv) * dv + bv0.y, 0.f);
    float v2 = fmaxf((aa.z + s1.x * dv) * dv + bv0.z, 0.f);
    float v3 = fmaxf((aa.w + s1.y * dv) * dv + bv0.w, 0.f);
    float v4 = fmaxf((ab.x + s2.x * dv) * dv + bv1.x, 0.f);
    float v5 = fmaxf((ab.y + s2.y * dv) * dv + bv1.y, 0.f);
    float v6 = fmaxf((ab.z + s3.x * dv) * dv + bv1.z, 0.f);
    float v7 = fmaxf((ab.w + s3.y * dv) * dv + bv1.w, 0.f);
    if (lane < 8) {
        uint4 st;
        ((__half2*)&st)[0] = __floats2half2_rn(v0, v1);
        ((__half2*)&st)[1] = __floats2half2_rn(v2, v3);
        ((__half2*)&st)[2] = __floats2half2_rn(v4, v5);
        ((__half2*)&st)[3] = __floats2half2_rn(v6, v7);
        ((uint4*)(out + ((size_t)row << 6)))[q] = st;
    }
}

// --- LDS-tiled GEMM (layer 2): hs = (h1b@W2)*dinv, fp16 in/out, COUT=40. ----
template<int COUT>
__global__ void k_gemm(const __half* __restrict__ xin,
                       const float* __restrict__ W,
                       const float* __restrict__ dinv,
                       __half* __restrict__ hs, int n) {
    __shared__ float Wl[64 * 68];
    __shared__ float Xl[64 * 68];
    int t  = threadIdx.x;
    int tr = t >> 4, tc = t & 15;
    int base = blockIdx.x * 64;

    for (int i = t; i < 64 * 17; i += 256) {
        int k = i / 17, c4 = (i % 17) * 4;
        float4 w = make_float4(0.f, 0.f, 0.f, 0.f);
        if (c4 < COUT) w = *(const float4*)&W[k * COUT + c4];
        *(float4*)&Wl[k * 68 + c4] = w;
    }
    for (int rr = tr; rr < 64; rr += 16) {
        int row = base + rr; if (row >= n) row = n - 1;
        uint2 u = *(const uint2*)&xin[(size_t)row * 64 + tc * 4];
        float2 a = __half22float2(*(__half2*)&u.x);
        float2 c = __half22float2(*(__half2*)&u.y);
        Xl[(tc * 4 + 0) * 68 + rr] = a.x;
        Xl[(tc * 4 + 1) * 68 + rr] = a.y;
        Xl[(tc * 4 + 2) * 68 + rr] = c.x;
        Xl[(tc * 4 + 3) * 68 + rr] = c.y;
    }
    __syncthreads();

    float acc[4][4] = {{0.f}};
#pragma unroll 8
    for (int k = 0; k < 64; ++k) {
        float4 xv = *(const float4*)&Xl[k * 68 + tr * 4];
        float4 wv = *(const float4*)&Wl[k * 68 + tc * 4];
        acc[0][0] = fmaf(xv.x, wv.x, acc[0][0]);
        acc[0][1] = fmaf(xv.x, wv.y, acc[0][1]);
        acc[0][2] = fmaf(xv.x, wv.z, acc[0][2]);
        acc[0][3] = fmaf(xv.x, wv.w, acc[0][3]);
        acc[1][0] = fmaf(xv.y, wv.x, acc[1][0]);
        acc[1][1] = fmaf(xv.y, wv.y, acc[1][1]);
        acc[1][2] = fmaf(xv.y, wv.z, acc[1][2]);
        acc[1][3] = fmaf(xv.y, wv.w, acc[1][3]);
        acc[2][0] = fmaf(xv.z, wv.x, acc[2][0]);
        acc[2][1] = fmaf(xv.z, wv.y, acc[2][1]);
        acc[2][2] = fmaf(xv.z, wv.z, acc[2][2]);
        acc[2][3] = fmaf(xv.z, wv.w, acc[2][3]);
        acc[3][0] = fmaf(xv.w, wv.x, acc[3][0]);
        acc[3][1] = fmaf(xv.w, wv.y, acc[3][1]);
        acc[3][2] = fmaf(xv.w, wv.z, acc[3][2]);
        acc[3][3] = fmaf(xv.w, wv.w, acc[3][3]);
    }
#pragma unroll
    for (int i = 0; i < 4; ++i) {
        int r = base + tr * 4 + i;
        if (r >= n) break;
        float dv = dinv[r];
        __half2 p0 = __floats2half2_rn(acc[i][0] * dv, acc[i][1] * dv);
        __half2 p1 = __floats2half2_rn(acc[i][2] * dv, acc[i][3] * dv);
        if (tc * 4 + 3 < COUT) {
            *(__half2*)&hs[(size_t)r * COUT + tc * 4]     = p0;
            *(__half2*)&hs[(size_t)r * COUT + tc * 4 + 2] = p1;
        }
    }
}

// --- Gather C=40 + bias + log_softmax -> fp32. 4 edges x 16 lanes x 8B. -----
__global__ void k_gather_lsm40(const __half* __restrict__ hs,
                               const int* __restrict__ rbg,
                               const int* __restrict__ ren,
                               const unsigned short* __restrict__ ci,
                               const float* __restrict__ dinv,
                               const float* __restrict__ bias,
                               float* __restrict__ out, int n) {
    int row = blockIdx.x * 4 + (threadIdx.x >> 6);
    if (row >= n) return;
    int lane = threadIdx.x & 63;
    int g = lane >> 4, q = lane & 15;
    int beg = rbg[row], end = ren[row];

    // hoisted epilogue loads
    float dv = dinv[row];
    uint2 selfu = make_uint2(0u, 0u);
    if (q < 10)
        selfu = ((const uint2*)(hs + (size_t)row * 40))[q];

    float4 a = make_float4(0.f, 0.f, 0.f, 0.f);
    for (int base = beg; base < end; base += 64) {
        int mm = end - base; if (mm > 64) mm = 64;
        int idx = (lane < mm) ? (int)ci[base + lane] : 0;
        for (int j = 0; 4 * j < mm; ++j) {
            int s = __shfl(idx, 4 * j + g, 64);
            if (q < 10 && base + 4 * j + g < end) {
                uint2 u = ((const uint2*)(hs + (size_t)s * 40))[q];
                float2 f0 = __half22float2(*(__half2*)&u.x);
                float2 f1 = __half22float2(*(__half2*)&u.y);
                a.x += f0.x; a.y += f0.y; a.z += f1.x; a.w += f1.y;
            }
        }
    }
    a.x += __shfl_xor(a.x, 16, 64); a.y += __shfl_xor(a.y, 16, 64);
    a.z += __shfl_xor(a.z, 16, 64); a.w += __shfl_xor(a.w, 16, 64);
    a.x += __shfl_xor(a.x, 32, 64); a.y += __shfl_xor(a.y, 32, 64);
    a.z += __shfl_xor(a.z, 32, 64); a.w += __shfl_xor(a.w, 32, 64);

    float2 s0 = __half22float2(*(__half2*)&selfu.x);
    float2 s1 = __half22float2(*(__half2*)&selfu.y);
    float v0 = -INFINITY, v1 = -INFINITY, v2 = -INFINITY, v3 = -INFINITY;
    if (q < 10) {
        float4 bv = *(const float4*)&bias[q * 4];
        v0 = (a.x + s0.x) * dv + bv.x;
        v1 = (a.y + s0.y) * dv + bv.y;
        v2 = (a.z + s1.x) * dv + bv.z;
        v3 = (a.w + s1.y) * dv + bv.w;
    }
    float mx = fmaxf(fmaxf(v0, v1), fmaxf(v2, v3));
#pragma unroll
    for (int o = 1; o < 16; o <<= 1) mx = fmaxf(mx, __shfl_xor(mx, o, 64));
    float e0 = (q < 10) ? expf(v0 - mx) : 0.f;
    float e1 = (q < 10) ? expf(v1 - mx) : 0.f;
    float e2 = (q < 10) ? expf(v2 - mx) : 0.f;
    float e3 = (q < 10) ? expf(v3 - mx) : 0.f;
    float sm = (e0 + e1) + (e2 + e3);
#pragma unroll
    for (int o = 1; o < 16; o <<= 1) sm += __shfl_xor(sm, o, 64);
    if (lane < 16 && q < 10) {
        float ls = logf(sm);
        float4 r = make_float4(v0 - mx - ls, v1 - mx - ls,
                               v2 - mx - ls, v3 - mx - ls);
        *(float4*)&out[(size_t)row * 40 + q * 4] = r;
    }
}

extern "C" void kernel_launch(void* const* d_in, const int* in_sizes, int n_in,
                              void* d_out, int out_size, void* d_ws, size_t ws_size,
                              hipStream_t stream) {
    const float* x  = (const float*)d_in[0];
    const void*  ei = d_in[1];
    const float* W1 = (const float*)d_in[2];
    const float* b1 = (const float*)d_in[3];
    const float* W2 = (const float*)d_in[4];
    const float* b2 = (const float*)d_in[5];
    float* out = (float*)d_out;

    const int C_IN = 64;
    const int N = in_sizes[0] / C_IN;   // 50000
    const int E = in_sizes[1] / 2;      // 800000
    (void)n_in; (void)out_size; (void)ws_size;

    char* ws = (char*)d_ws;
    size_t off = 0;
    auto alloc = [&](size_t bytes) -> void* {
        void* p = ws + off;
        off += (bytes + 255) & ~(size_t)255;
        return p;
    };
    int*            bcur    = (int*)           alloc(NBMAX * 4);
    unsigned int*   ebkt    = (unsigned int*)  alloc((size_t)NBMAX * SLACK * 4);
    unsigned short* csr_src = (unsigned short*)alloc((size_t)NBMAX * SLACK * 2);
    int*            row_beg = (int*)           alloc((size_t)N * 4);
    int*            row_end = (int*)           alloc((size_t)N * 4);
    float*          dinv    = (float*)         alloc((size_t)N * 4);
    unsigned char*  hs8     = (unsigned char*) alloc((size_t)N * 64);
    __half*         h1b     = (__half*)        alloc((size_t)N * 64 * 2);
    __half*         hs2     = (__half*)        alloc((size_t)N * 40 * 2);

    const int nb    = (N + RPB - 1) >> SHIFT;         // 196
    const int ngrid = (N + 63) / 64;                  // 782
    const int npart = (E + CHUNK_P - 1) / CHUNK_P;    // 196

    // bcur init via H2D memcpy node (replaces the k_init dispatch)
    static int h_binit[NBMAX];
    for (int i = 0; i < NBMAX; ++i) h_binit[i] = i * SLACK;
    (void)hipMemcpyAsync(bcur, h_binit, NBMAX * sizeof(int),
                         hipMemcpyHostToDevice, stream);

    k_part_gemm<<<npart + ngrid, 256, 0, stream>>>(
        (const int*)ei, bcur, ebkt, E, nb, npart, x, W1, hs8, N);
    k_build<<<nb, 256, 0, stream>>>(ebkt, bcur, row_beg, row_end, dinv,
                                    csr_src, N);
    k_gather_relu64<<<(N + 3) / 4, 256, 0, stream>>>(
        hs8, row_beg, row_end, csr_src, dinv, b1, h1b, N);
    k_gemm<40><<<ngrid, 256, 0, stream>>>(h1b, W2, dinv, hs2, N);
    k_gather_lsm40<<<(N + 3) / 4, 256, 0, stream>>>(
        hs2, row_beg, row_end, csr_src, dinv, b2, out, N);
}

// Round 11
// 98.428 us; speedup vs baseline: 1.1078x; 1.0005x over previous
//
#include <hip/hip_runtime.h>
#include <hip/hip_fp16.h>
#include <math.h>

// ---------------------------------------------------------------------------
// 2-layer GCN on MI355X. N=50000 (<2^16), E=800000, C: 64 -> 64 -> 40.
// hs8[i] = fp8_e4m3((x@W1)[i])  (quantized in gemm1 epilogue; 3.2MB);
// h1b[d] = relu((hs8[d]*dinv[d] + sum_e hs8[src]*dinv[src]) * dinv[d] + b1);
// hs2[i] = (h1b@W2)[i]*dinv[i] (fp16);
// out[d] = log_softmax((hs2[d] + sum_e hs2[src]) * dinv[d] + b2).
//
// 5 dispatches + 1 H2D memcpy node:
//   memcpyAsync: bcur[b] = b*SLACK.
//   k_part_gemm: blocks [0,npart) partition edges into slack dst-buckets
//                (single-pass: 16KB LDS stash + histogram; low-dword int64
//                reads; COOPERATIVE is64 detect -- the old thread-0 serial
//                64-load loop was a ~6us prologue on every partition block).
//                CHUNK_P=4096 keeps npart+ngrid=978 <= 1024 co-residency
//                slots (the r10 surplus win: single scheduling round).
//                Blocks [npart,..) run LDS-tiled x@W1, fp8 e4m3 out.
//   k_build:     one wg per 256-row bucket; wave-level shfl_up scan ->
//                row_beg/row_end/dinv -> bucket-local ushort CSR fill.
//   k_gather_relu64: wave/dst-row (1 row/wave, 50000 waves); 8 edges x
//                8 lanes x uint2 (8 fp8 ch); packed cvt_pk_f32_fp8;
//                dinv[src] fmaf (broadcast probe ~free, r18);
//                3 shfl_xor butterflies; bias+relu -> fp16 h1b.
//   k_gemm<40>:  LDS-tiled h1b@W2, dinv-scaled fp16 out.
//   k_gather_lsm40: wave/dst-row; 4 edges x 16 lanes x 8B; fused bias +
//                log_softmax -> fp32.
// Lessons: random small global stores amplify unless bucket-local (r3-5);
// gather fusion loses ~10us (r10/r11); bulk RMW at low block-parallelism
// loses (r12); fixed-cost cuts won 7.2us (r13); gather chain/byte/probe
// cuts all null (r14/r17/r18) -> gathers are scattered-vmem floored;
// r19 won 7.2us via single-round scheduling (keep grid <= 1024 blocks).
// ---------------------------------------------------------------------------

#define SHIFT   8
#define RPB     256
#define NBMAX   256
#define SLACK   8192
#define CHUNK_P 4096

typedef float v2f __attribute__((ext_vector_type(2)));

// --- fused: edge partition (blocks < npart) || x@W1 GEMM (rest) -------------
__global__ void k_part_gemm(const int* __restrict__ ei32,
                            int* __restrict__ bcur,
                            unsigned int* __restrict__ ebkt, int E, int nb,
                            int npart,
                            const float* __restrict__ x,
                            const float* __restrict__ W1,
                            unsigned char* __restrict__ hs8, int n) {
    __shared__ __align__(16) float smem[2 * 64 * 68];
    if ((int)blockIdx.x < npart) {
        // ---------------- partition branch (single-pass, LDS stash) --------
        int* cnt   = (int*)smem;          // [256]
        int* rbase = cnt + 256;           // [256]
        int* is64p = rbase + 256;         // [1]
        int* stash = is64p + 1;           // [4096] packed (dst16|src16)
        int t = threadIdx.x;
        cnt[t] = 0;
        // cooperative is64 detect: wave 0 tests 64 high-dwords in parallel
        // (replaces thread-0's serial 64-load loop = ~6us/block prologue).
        if (t < 64) {
            int bad = (ei32[2 * t + 1] != 0) ? 1 : 0;
            unsigned long long m = __ballot(bad);
            if (t == 0) *is64p = (m == 0ULL) ? 1 : 0;
        }
        __syncthreads();
        int is64 = *is64p;
        int lo = blockIdx.x * CHUNK_P;
        int hi = lo + CHUNK_P; if (hi > E) hi = E;
        for (int e = lo + t; e < hi; e += 256) {
            int s, d;
            if (is64) { s = ei32[2 * e]; d = ei32[2 * (E + e)]; }  // low dwords
            else      { s = ei32[e];     d = ei32[E + e]; }
            stash[e - lo] = (int)(((unsigned int)d << 16) | (unsigned int)s);
            atomicAdd(&cnt[d >> SHIFT], 1);
        }
        __syncthreads();
        {
            int c = cnt[t];
            rbase[t] = c ? atomicAdd(&bcur[t], c) : 0;
            cnt[t] = 0;
        }
        __syncthreads();
        for (int e = lo + t; e < hi; e += 256) {
            unsigned int v = (unsigned int)stash[e - lo];
            int b = (int)(v >> 16) >> SHIFT;
            int pos = rbase[b] + atomicAdd(&cnt[b], 1);
            ebkt[pos] = (((v >> 16) & (RPB - 1)) << 16) | (v & 0xffffu);
        }
    } else {
        // ---------------- GEMM branch (x@W1, fp8 e4m3 out) ------------------
        float* Wl = smem;
        float* Xl = smem + 64 * 68;
        int t  = threadIdx.x;
        int tr = t >> 4, tc = t & 15;
        int base = (blockIdx.x - npart) * 64;

        for (int i = t; i < 64 * 17; i += 256) {
            int k = i / 17, c4 = (i % 17) * 4;
            float4 w = make_float4(0.f, 0.f, 0.f, 0.f);
            if (c4 < 64) w = *(const float4*)&W1[k * 64 + c4];
            *(float4*)&Wl[k * 68 + c4] = w;
        }
        for (int rr = tr; rr < 64; rr += 16) {
            int row = base + rr; if (row >= n) row = n - 1;
            float4 v = *(const float4*)&x[(size_t)row * 64 + tc * 4];
            Xl[(tc * 4 + 0) * 68 + rr] = v.x;
            Xl[(tc * 4 + 1) * 68 + rr] = v.y;
            Xl[(tc * 4 + 2) * 68 + rr] = v.z;
            Xl[(tc * 4 + 3) * 68 + rr] = v.w;
        }
        __syncthreads();

        float acc[4][4] = {{0.f}};
#pragma unroll 8
        for (int k = 0; k < 64; ++k) {
            float4 xv = *(const float4*)&Xl[k * 68 + tr * 4];
            float4 wv = *(const float4*)&Wl[k * 68 + tc * 4];
            acc[0][0] = fmaf(xv.x, wv.x, acc[0][0]);
            acc[0][1] = fmaf(xv.x, wv.y, acc[0][1]);
            acc[0][2] = fmaf(xv.x, wv.z, acc[0][2]);
            acc[0][3] = fmaf(xv.x, wv.w, acc[0][3]);
            acc[1][0] = fmaf(xv.y, wv.x, acc[1][0]);
            acc[1][1] = fmaf(xv.y, wv.y, acc[1][1]);
            acc[1][2] = fmaf(xv.y, wv.z, acc[1][2]);
            acc[1][3] = fmaf(xv.y, wv.w, acc[1][3]);
            acc[2][0] = fmaf(xv.z, wv.x, acc[2][0]);
            acc[2][1] = fmaf(xv.z, wv.y, acc[2][1]);
            acc[2][2] = fmaf(xv.z, wv.z, acc[2][2]);
            acc[2][3] = fmaf(xv.z, wv.w, acc[2][3]);
            acc[3][0] = fmaf(xv.w, wv.x, acc[3][0]);
            acc[3][1] = fmaf(xv.w, wv.y, acc[3][1]);
            acc[3][2] = fmaf(xv.w, wv.z, acc[3][2]);
            acc[3][3] = fmaf(xv.w, wv.w, acc[3][3]);
        }
#pragma unroll
        for (int i = 0; i < 4; ++i) {
            int r = base + tr * 4 + i;
            if (r >= n) break;
            unsigned int w;
            w = (unsigned int)__builtin_amdgcn_cvt_pk_fp8_f32(
                    acc[i][0], acc[i][1], 0, false);
            w = (unsigned int)__builtin_amdgcn_cvt_pk_fp8_f32(
                    acc[i][2], acc[i][3], (int)w, true);
            ((unsigned int*)(hs8 + ((size_t)r << 6)))[tc] = w;
        }
    }
}

// --- per-bucket (256 rows): degree, wave-scan, row_beg/row_end/dinv, CSR ----
__global__ void k_build(const unsigned int* __restrict__ ebkt,
                        const int* __restrict__ bcur,
                        int* __restrict__ row_beg, int* __restrict__ row_end,
                        float* __restrict__ dinv,
                        unsigned short* __restrict__ csr_src, int N) {
    __shared__ int cnt[RPB];
    __shared__ int wtot[4];
    int t = threadIdx.x, b = blockIdx.x;
    int rows0 = b << SHIFT;
    cnt[t] = 0;
    __syncthreads();
    int lo = b * SLACK, hi = bcur[b];
    for (int e = lo + t; e < hi; e += 256)
        atomicAdd(&cnt[ebkt[e] >> 16], 1);
    __syncthreads();
    int c = cnt[t];
    // wave-level inclusive scan (64 lanes), then cross-wave fixup: 1 barrier.
    int lane = t & 63, w = t >> 6;
    int sc = c;
#pragma unroll
    for (int o = 1; o < 64; o <<= 1) {
        int u = __shfl_up(sc, o, 64);
        if (lane >= o) sc += u;
    }
    if (lane == 63) wtot[w] = sc;
    __syncthreads();
    int wbase = 0;
#pragma unroll
    for (int ww = 0; ww < 3; ++ww)
        if (ww < w) wbase += wtot[ww];
    int beg = lo + wbase + sc - c;       // exclusive prefix
    int row = rows0 + t;
    if (row < N) {
        row_beg[row] = beg; row_end[row] = beg + c;
        dinv[row] = rsqrtf((float)c + 1.0f);
    }
    cnt[t] = beg;
    __syncthreads();
    for (int e = lo + t; e < hi; e += 256) {
        unsigned int v = ebkt[e];
        int pos = atomicAdd(&cnt[v >> 16], 1);
        csr_src[pos] = (unsigned short)(v & 0xffffu);
    }
}

// --- Gather C=64 fp8: 8 edges x 8 lanes x uint2 (8 fp8 ch, packed cvt); -----
// --- fused dinv[src] scale + bias + relu -> fp16 h1b. -----------------------
__global__ void k_gather_relu64(const unsigned char* __restrict__ hs8,
                                const int* __restrict__ rbg,
                                const int* __restrict__ ren,
                                const unsigned short* __restrict__ ci,
                                const float* __restrict__ dinv,
                                const float* __restrict__ bias,
                                __half* __restrict__ out, int n) {
    int row = blockIdx.x * 4 + (threadIdx.x >> 6);
    if (row >= n) return;
    int lane = threadIdx.x & 63;
    int g = lane >> 3, q = lane & 7;     // edge slot 0..7, 8B chunk 0..7
    int beg = rbg[row], end = ren[row];

    // hoisted epilogue loads (issue under the gather loop)
    float dv = dinv[row];
    uint2 su = ((const uint2*)(hs8 + ((size_t)row << 6)))[q];

    float4 aa = make_float4(0.f, 0.f, 0.f, 0.f);
    float4 ab = make_float4(0.f, 0.f, 0.f, 0.f);
    for (int base = beg; base < end; base += 64) {
        int mm = end - base; if (mm > 64) mm = 64;
        int idx = (lane < mm) ? (int)ci[base + lane] : 0;
        for (int j = 0; 8 * j < mm; ++j) {
            int e = 8 * j + g;
            int s = __shfl(idx, e, 64);
            if (base + e < end) {
                float ds = dinv[s];
                uint2 u = ((const uint2*)(hs8 + ((size_t)s << 6)))[q];
                v2f f0 = __builtin_amdgcn_cvt_pk_f32_fp8((int)u.x, false);
                v2f f1 = __builtin_amdgcn_cvt_pk_f32_fp8((int)u.x, true);
                v2f f2 = __builtin_amdgcn_cvt_pk_f32_fp8((int)u.y, false);
                v2f f3 = __builtin_amdgcn_cvt_pk_f32_fp8((int)u.y, true);
                aa.x = fmaf(f0.x, ds, aa.x); aa.y = fmaf(f0.y, ds, aa.y);
                aa.z = fmaf(f1.x, ds, aa.z); aa.w = fmaf(f1.y, ds, aa.w);
                ab.x = fmaf(f2.x, ds, ab.x); ab.y = fmaf(f2.y, ds, ab.y);
                ab.z = fmaf(f3.x, ds, ab.z); ab.w = fmaf(f3.y, ds, ab.w);
            }
        }
    }
#pragma unroll
    for (int o = 8; o < 64; o <<= 1) {
        aa.x += __shfl_xor(aa.x, o, 64); aa.y += __shfl_xor(aa.y, o, 64);
        aa.z += __shfl_xor(aa.z, o, 64); aa.w += __shfl_xor(aa.w, o, 64);
        ab.x += __shfl_xor(ab.x, o, 64); ab.y += __shfl_xor(ab.y, o, 64);
        ab.z += __shfl_xor(ab.z, o, 64); ab.w += __shfl_xor(ab.w, o, 64);
    }
    // epilogue on all lanes (values identical within each q); lanes<8 store
    v2f s0 = __builtin_amdgcn_cvt_pk_f32_fp8((int)su.x, false);
    v2f s1 = __builtin_amdgcn_cvt_pk_f32_fp8((int)su.x, true);
    v2f s2 = __builtin_amdgcn_cvt_pk_f32_fp8((int)su.y, false);
    v2f s3 = __builtin_amdgcn_cvt_pk_f32_fp8((int)su.y, true);
    float4 bv0 = *(const float4*)&bias[q * 8];
    float4 bv1 = *(const float4*)&bias[q * 8 + 4];
    float v0 = fmaxf((aa.x + s0.x * dv) * dv + bv0.x, 0.f);
    float v1 = fmaxf((aa.y + s0.y * dv) * dv + bv0.y, 0.f);
    float v2 = fmaxf((aa.z + s1.x * dv) * dv + bv0.z, 0.f);
    float v3 = fmaxf((aa.w + s1.y * dv) * dv + bv0.w, 0.f);
    float v4 = fmaxf((ab.x + s2.x * dv) * dv + bv1.x, 0.f);
    float v5 = fmaxf((ab.y + s2.y * dv) * dv + bv1.y, 0.f);
    float v6 = fmaxf((ab.z + s3.x * dv) * dv + bv1.z, 0.f);
    float v7 = fmaxf((ab.w + s3.y * dv) * dv + bv1.w, 0.f);
    if (lane < 8) {
        uint4 st;
        ((__half2*)&st)[0] = __floats2half2_rn(v0, v1);
        ((__half2*)&st)[1] = __floats2half2_rn(v2, v3);
        ((__half2*)&st)[2] = __floats2half2_rn(v4, v5);
        ((__half2*)&st)[3] = __floats2half2_rn(v6, v7);
        ((uint4*)(out + ((size_t)row << 6)))[q] = st;
    }
}

// --- LDS-tiled GEMM (layer 2): hs = (h1b@W2)*dinv, fp16 in/out, COUT=40. ----
template<int COUT>
__global__ void k_gemm(const __half* __restrict__ xin,
                       const float* __restrict__ W,
                       const float* __restrict__ dinv,
                       __half* __restrict__ hs, int n) {
    __shared__ float Wl[64 * 68];
    __shared__ float Xl[64 * 68];
    int t  = threadIdx.x;
    int tr = t >> 4, tc = t & 15;
    int base = blockIdx.x * 64;

    for (int i = t; i < 64 * 17; i += 256) {
        int k = i / 17, c4 = (i % 17) * 4;
        float4 w = make_float4(0.f, 0.f, 0.f, 0.f);
        if (c4 < COUT) w = *(const float4*)&W[k * COUT + c4];
        *(float4*)&Wl[k * 68 + c4] = w;
    }
    for (int rr = tr; rr < 64; rr += 16) {
        int row = base + rr; if (row >= n) row = n - 1;
        uint2 u = *(const uint2*)&xin[(size_t)row * 64 + tc * 4];
        float2 a = __half22float2(*(__half2*)&u.x);
        float2 c = __half22float2(*(__half2*)&u.y);
        Xl[(tc * 4 + 0) * 68 + rr] = a.x;
        Xl[(tc * 4 + 1) * 68 + rr] = a.y;
        Xl[(tc * 4 + 2) * 68 + rr] = c.x;
        Xl[(tc * 4 + 3) * 68 + rr] = c.y;
    }
    __syncthreads();

    float acc[4][4] = {{0.f}};
#pragma unroll 8
    for (int k = 0; k < 64; ++k) {
        float4 xv = *(const float4*)&Xl[k * 68 + tr * 4];
        float4 wv = *(const float4*)&Wl[k * 68 + tc * 4];
        acc[0][0] = fmaf(xv.x, wv.x, acc[0][0]);
        acc[0][1] = fmaf(xv.x, wv.y, acc[0][1]);
        acc[0][2] = fmaf(xv.x, wv.z, acc[0][2]);
        acc[0][3] = fmaf(xv.x, wv.w, acc[0][3]);
        acc[1][0] = fmaf(xv.y, wv.x, acc[1][0]);
        acc[1][1] = fmaf(xv.y, wv.y, acc[1][1]);
        acc[1][2] = fmaf(xv.y, wv.z, acc[1][2]);
        acc[1][3] = fmaf(xv.y, wv.w, acc[1][3]);
        acc[2][0] = fmaf(xv.z, wv.x, acc[2][0]);
        acc[2][1] = fmaf(xv.z, wv.y, acc[2][1]);
        acc[2][2] = fmaf(xv.z, wv.z, acc[2][2]);
        acc[2][3] = fmaf(xv.z, wv.w, acc[2][3]);
        acc[3][0] = fmaf(xv.w, wv.x, acc[3][0]);
        acc[3][1] = fmaf(xv.w, wv.y, acc[3][1]);
        acc[3][2] = fmaf(xv.w, wv.z, acc[3][2]);
        acc[3][3] = fmaf(xv.w, wv.w, acc[3][3]);
    }
#pragma unroll
    for (int i = 0; i < 4; ++i) {
        int r = base + tr * 4 + i;
        if (r >= n) break;
        float dv = dinv[r];
        __half2 p0 = __floats2half2_rn(acc[i][0] * dv, acc[i][1] * dv);
        __half2 p1 = __floats2half2_rn(acc[i][2] * dv, acc[i][3] * dv);
        if (tc * 4 + 3 < COUT) {
            *(__half2*)&hs[(size_t)r * COUT + tc * 4]     = p0;
            *(__half2*)&hs[(size_t)r * COUT + tc * 4 + 2] = p1;
        }
    }
}

// --- Gather C=40 + bias + log_softmax -> fp32. 4 edges x 16 lanes x 8B. -----
__global__ void k_gather_lsm40(const __half* __restrict__ hs,
                               const int* __restrict__ rbg,
                               const int* __restrict__ ren,
                               const unsigned short* __restrict__ ci,
                               const float* __restrict__ dinv,
                               const float* __restrict__ bias,
                               float* __restrict__ out, int n) {
    int row = blockIdx.x * 4 + (threadIdx.x >> 6);
    if (row >= n) return;
    int lane = threadIdx.x & 63;
    int g = lane >> 4, q = lane & 15;
    int beg = rbg[row], end = ren[row];

    // hoisted epilogue loads
    float dv = dinv[row];
    uint2 selfu = make_uint2(0u, 0u);
    if (q < 10)
        selfu = ((const uint2*)(hs + (size_t)row * 40))[q];

    float4 a = make_float4(0.f, 0.f, 0.f, 0.f);
    for (int base = beg; base < end; base += 64) {
        int mm = end - base; if (mm > 64) mm = 64;
        int idx = (lane < mm) ? (int)ci[base + lane] : 0;
        for (int j = 0; 4 * j < mm; ++j) {
            int s = __shfl(idx, 4 * j + g, 64);
            if (q < 10 && base + 4 * j + g < end) {
                uint2 u = ((const uint2*)(hs + (size_t)s * 40))[q];
                float2 f0 = __half22float2(*(__half2*)&u.x);
                float2 f1 = __half22float2(*(__half2*)&u.y);
                a.x += f0.x; a.y += f0.y; a.z += f1.x; a.w += f1.y;
            }
        }
    }
    a.x += __shfl_xor(a.x, 16, 64); a.y += __shfl_xor(a.y, 16, 64);
    a.z += __shfl_xor(a.z, 16, 64); a.w += __shfl_xor(a.w, 16, 64);
    a.x += __shfl_xor(a.x, 32, 64); a.y += __shfl_xor(a.y, 32, 64);
    a.z += __shfl_xor(a.z, 32, 64); a.w += __shfl_xor(a.w, 32, 64);

    float2 s0 = __half22float2(*(__half2*)&selfu.x);
    float2 s1 = __half22float2(*(__half2*)&selfu.y);
    float v0 = -INFINITY, v1 = -INFINITY, v2 = -INFINITY, v3 = -INFINITY;
    if (q < 10) {
        float4 bv = *(const float4*)&bias[q * 4];
        v0 = (a.x + s0.x) * dv + bv.x;
        v1 = (a.y + s0.y) * dv + bv.y;
        v2 = (a.z + s1.x) * dv + bv.z;
        v3 = (a.w + s1.y) * dv + bv.w;
    }
    float mx = fmaxf(fmaxf(v0, v1), fmaxf(v2, v3));
#pragma unroll
    for (int o = 1; o < 16; o <<= 1) mx = fmaxf(mx, __shfl_xor(mx, o, 64));
    float e0 = (q < 10) ? expf(v0 - mx) : 0.f;
    float e1 = (q < 10) ? expf(v1 - mx) : 0.f;
    float e2 = (q < 10) ? expf(v2 - mx) : 0.f;
    float e3 = (q < 10) ? expf(v3 - mx) : 0.f;
    float sm = (e0 + e1) + (e2 + e3);
#pragma unroll
    for (int o = 1; o < 16; o <<= 1) sm += __shfl_xor(sm, o, 64);
    if (lane < 16 && q < 10) {
        float ls = logf(sm);
        float4 r = make_float4(v0 - mx - ls, v1 - mx - ls,
                               v2 - mx - ls, v3 - mx - ls);
        *(float4*)&out[(size_t)row * 40 + q * 4] = r;
    }
}

extern "C" void kernel_launch(void* const* d_in, const int* in_sizes, int n_in,
                              void* d_out, int out_size, void* d_ws, size_t ws_size,
                              hipStream_t stream) {
    const float* x  = (const float*)d_in[0];
    const void*  ei = d_in[1];
    const float* W1 = (const float*)d_in[2];
    const float* b1 = (const float*)d_in[3];
    const float* W2 = (const float*)d_in[4];
    const float* b2 = (const float*)d_in[5];
    float* out = (float*)d_out;

    const int C_IN = 64;
    const int N = in_sizes[0] / C_IN;   // 50000
    const int E = in_sizes[1] / 2;      // 800000
    (void)n_in; (void)out_size; (void)ws_size;

    char* ws = (char*)d_ws;
    size_t off = 0;
    auto alloc = [&](size_t bytes) -> void* {
        void* p = ws + off;
        off += (bytes + 255) & ~(size_t)255;
        return p;
    };
    int*            bcur    = (int*)           alloc(NBMAX * 4);
    unsigned int*   ebkt    = (unsigned int*)  alloc((size_t)NBMAX * SLACK * 4);
    unsigned short* csr_src = (unsigned short*)alloc((size_t)NBMAX * SLACK * 2);
    int*            row_beg = (int*)           alloc((size_t)N * 4);
    int*            row_end = (int*)           alloc((size_t)N * 4);
    float*          dinv    = (float*)         alloc((size_t)N * 4);
    unsigned char*  hs8     = (unsigned char*) alloc((size_t)N * 64);
    __half*         h1b     = (__half*)        alloc((size_t)N * 64 * 2);
    __half*         hs2     = (__half*)        alloc((size_t)N * 40 * 2);

    const int nb    = (N + RPB - 1) >> SHIFT;         // 196
    const int ngrid = (N + 63) / 64;                  // 782
    const int npart = (E + CHUNK_P - 1) / CHUNK_P;    // 196

    // bcur init via H2D memcpy node (replaces the k_init dispatch)
    static int h_binit[NBMAX];
    for (int i = 0; i < NBMAX; ++i) h_binit[i] = i * SLACK;
    (void)hipMemcpyAsync(bcur, h_binit, NBMAX * sizeof(int),
                         hipMemcpyHostToDevice, stream);

    k_part_gemm<<<npart + ngrid, 256, 0, stream>>>(
        (const int*)ei, bcur, ebkt, E, nb, npart, x, W1, hs8, N);
    k_build<<<nb, 256, 0, stream>>>(ebkt, bcur, row_beg, row_end, dinv,
                                    csr_src, N);
    k_gather_relu64<<<(N + 3) / 4, 256, 0, stream>>>(
        hs8, row_beg, row_end, csr_src, dinv, b1, h1b, N);
    k_gemm<40><<<ngrid, 256, 0, stream>>>(h1b, W2, dinv, hs2, N);
    k_gather_lsm40<<<(N + 3) / 4, 256, 0, stream>>>(
        hs2, row_beg, row_end, csr_src, dinv, b2, out, N);
}